// Round 1
// baseline (1766.142 us; speedup 1.0000x reference)
//
#include <hip/hip_runtime.h>
#include <math.h>

#define N_NODES 50000
#define E_EDGES 800000
#define IN_DIM  128
#define HID     64
#define KF      4
#define EXP_HID 64

// d_out layout (float32, concatenated in return order):
//   disen_graph_emb (K*HID = 256) | Z (N*K*HID = 12,800,000) |
//   e_h_final (E = 800,000)       | e_h_all (K*E = 3,200,000)
#define OFF_DISEN 0
#define OFF_Z     (KF*HID)
#define OFF_EHF   (OFF_Z + N_NODES*KF*HID)
#define OFF_EHALL (OFF_EHF + E_EDGES)

#define NPB 8   // nodes per block in z_kernel (50000 = 6250 * 8, exact)

// ---------------------------------------------------------------------------
// Kernel 1: Z[n,k,h] = relu(x[n,:] @ W_init[k,:,h] + b_init[k,h]), then
// row-normalize over h. Block = 256 threads (4 waves; wave w == k slice),
// 8 nodes per block so each W element is reused 8x from registers.
// ---------------------------------------------------------------------------
__global__ __launch_bounds__(256) void z_kernel(
    const float* __restrict__ x, const float* __restrict__ W,
    const float* __restrict__ b, float* __restrict__ out) {
  __shared__ __align__(16) float xs[NPB * IN_DIM];
  const int tid = threadIdx.x;
  const int n0 = blockIdx.x * NPB;

  // stage 8 x-rows (1024 floats) as 256 float4 loads
  ((float4*)xs)[tid] = ((const float4*)(x + n0 * IN_DIM))[tid];
  __syncthreads();

  const int k = tid >> 6;   // wave index == disentangle factor
  const int h = tid & 63;   // lane == hidden channel

  const float bias = b[k * HID + h];
  float acc[NPB];
#pragma unroll
  for (int j = 0; j < NPB; ++j) acc[j] = bias;

  const float* wp = W + k * IN_DIM * HID + h;   // coalesced over h
  for (int i = 0; i < IN_DIM; ++i) {
    const float w = wp[i * HID];
#pragma unroll
    for (int j = 0; j < NPB; ++j)
      acc[j] = fmaf(xs[j * IN_DIM + i], w, acc[j]);  // LDS broadcast read
  }

  float* zout = out + OFF_Z + n0 * (KF * HID) + k * HID + h;
#pragma unroll
  for (int j = 0; j < NPB; ++j) {
    float z = fmaxf(acc[j], 0.f);
    float s = z * z;
#pragma unroll
    for (int d = 1; d < 64; d <<= 1) s += __shfl_xor(s, d, 64);  // wave=64
    zout[j * (KF * HID)] = z / fmaxf(sqrtf(s), 1e-12f);
  }
}

// ---------------------------------------------------------------------------
// Kernel 2a/2b: disen_graph_emb[k,h] = max_n Z[n,k,h]. Z >= 0, so uint-punned
// atomicMax is order-exact (deterministic). Init region to 0 first.
// ---------------------------------------------------------------------------
__global__ void disen_init_kernel(float* __restrict__ disen) {
  disen[threadIdx.x] = 0.f;
}

__global__ __launch_bounds__(256) void disen_max_kernel(
    const float* __restrict__ Z, float* __restrict__ disen) {
  const int tid = threadIdx.x;                       // tid == (k,h) column
  const int chunk = (N_NODES + gridDim.x - 1) / gridDim.x;
  const int s = blockIdx.x * chunk;
  const int e = min(s + chunk, N_NODES);
  float m = 0.f;
  for (int n = s; n < e; ++n)                        // coalesced: 256 consecutive
    m = fmaxf(m, Z[n * (KF * HID) + tid]);
  atomicMax((unsigned int*)(disen + tid), __float_as_uint(m));
}

// ---------------------------------------------------------------------------
// Kernel 3: per edge e, per k:
//   h_o  = relu( sum_h Zs[h]*W1s[h,o] + Zd[h]*W1d[h,o] + b1[o] )
//   e_k  = sum_o h_o * W2[o] + b2
// lane = edge (64 edges/wave). acc[64] lives in VGPRs (all indices static
// after unroll). Weights in LDS, read with wave-uniform addresses ->
// broadcast ds_read_b128, conflict-free. Every v_fmac is a real MAC.
// ---------------------------------------------------------------------------
__global__ __launch_bounds__(256) void edge_kernel(
    const int* __restrict__ ei, const float* __restrict__ W1,
    const float* __restrict__ b1, const float* __restrict__ W2,
    const float* __restrict__ b2, const float* __restrict__ Z,
    float* __restrict__ ehf, float* __restrict__ ehall) {
  __shared__ __align__(16) float w1s[HID * EXP_HID];  // [h][o], rows contiguous
  __shared__ __align__(16) float w1d[HID * EXP_HID];
  __shared__ __align__(16) float w2s[EXP_HID];
  __shared__ __align__(16) float b1s[EXP_HID];

  const int tid = threadIdx.x;
#pragma unroll
  for (int r = 0; r < 4; ++r)
    ((float4*)w1s)[r * 256 + tid] = ((const float4*)W1)[r * 256 + tid];
#pragma unroll
  for (int r = 0; r < 4; ++r)
    ((float4*)w1d)[r * 256 + tid] =
        ((const float4*)(W1 + HID * EXP_HID))[r * 256 + tid];
  if (tid < EXP_HID) { w2s[tid] = W2[tid]; b1s[tid] = b1[tid]; }
  __syncthreads();

  const float bias2 = b2[0];
  const int e = blockIdx.x * 256 + tid;     // grid exact: 3125*256 = 800000
  const int src = ei[e];
  const int dst = ei[E_EDGES + e];
  const float* zs_base = Z + src * (KF * HID);
  const float* zd_base = Z + dst * (KF * HID);

  float m = -INFINITY;
#pragma unroll 1
  for (int k = 0; k < KF; ++k) {
    const float4* zs4 = (const float4*)(zs_base + k * HID);
    const float4* zd4 = (const float4*)(zd_base + k * HID);

    float acc[EXP_HID];
#pragma unroll
    for (int o4 = 0; o4 < 16; ++o4) {
      const float4 bb = ((const float4*)b1s)[o4];
      acc[o4 * 4 + 0] = bb.x; acc[o4 * 4 + 1] = bb.y;
      acc[o4 * 4 + 2] = bb.z; acc[o4 * 4 + 3] = bb.w;
    }

#pragma unroll 1
    for (int h4 = 0; h4 < 16; ++h4) {
      const float4 a = zs4[h4];   // scattered 16B gather (L2/L3 resident)
      const float4 c = zd4[h4];
#pragma unroll
      for (int j = 0; j < 4; ++j) {
        const int h = h4 * 4 + j;
        const float as = (&a.x)[j];
        const float ad = (&c.x)[j];
        const float4* ws = (const float4*)(w1s + h * EXP_HID);
        const float4* wd = (const float4*)(w1d + h * EXP_HID);
#pragma unroll
        for (int o4 = 0; o4 < 16; ++o4) {
          const float4 w = ws[o4];   // uniform address -> LDS broadcast
          acc[o4 * 4 + 0] = fmaf(as, w.x, acc[o4 * 4 + 0]);
          acc[o4 * 4 + 1] = fmaf(as, w.y, acc[o4 * 4 + 1]);
          acc[o4 * 4 + 2] = fmaf(as, w.z, acc[o4 * 4 + 2]);
          acc[o4 * 4 + 3] = fmaf(as, w.w, acc[o4 * 4 + 3]);
          const float4 v = wd[o4];
          acc[o4 * 4 + 0] = fmaf(ad, v.x, acc[o4 * 4 + 0]);
          acc[o4 * 4 + 1] = fmaf(ad, v.y, acc[o4 * 4 + 1]);
          acc[o4 * 4 + 2] = fmaf(ad, v.z, acc[o4 * 4 + 2]);
          acc[o4 * 4 + 3] = fmaf(ad, v.w, acc[o4 * 4 + 3]);
        }
      }
    }

    float ek = bias2;
#pragma unroll
    for (int o = 0; o < EXP_HID; ++o)
      ek = fmaf(fmaxf(acc[o], 0.f), w2s[o], ek);

    ehall[k * E_EDGES + e] = ek;   // e_h_all[k, e], coalesced
    m = fmaxf(m, ek);
  }
  ehf[e] = m;                      // e_h_final[e]
}

// ---------------------------------------------------------------------------
extern "C" void kernel_launch(void* const* d_in, const int* in_sizes, int n_in,
                              void* d_out, int out_size, void* d_ws,
                              size_t ws_size, hipStream_t stream) {
  const float* x      = (const float*)d_in[0];
  const int*   ei     = (const int*)  d_in[1];
  const float* W_init = (const float*)d_in[2];
  const float* b_init = (const float*)d_in[3];
  const float* W1     = (const float*)d_in[4];
  const float* b1     = (const float*)d_in[5];
  const float* W2     = (const float*)d_in[6];
  const float* b2     = (const float*)d_in[7];
  float* out = (float*)d_out;

  z_kernel<<<N_NODES / NPB, 256, 0, stream>>>(x, W_init, b_init, out);
  disen_init_kernel<<<1, KF * HID, 0, stream>>>(out + OFF_DISEN);
  disen_max_kernel<<<256, 256, 0, stream>>>(out + OFF_Z, out + OFF_DISEN);
  edge_kernel<<<E_EDGES / 256, 256, 0, stream>>>(
      ei, W1, b1, W2, b2, out + OFF_Z, out + OFF_EHF, out + OFF_EHALL);
}

// Round 2
// 635.346 us; speedup vs baseline: 2.7798x; 2.7798x over previous
//
#include <hip/hip_runtime.h>
#include <math.h>

#define N_NODES 50000
#define E_EDGES 800000
#define IN_DIM  128
#define HID     64
#define KF      4
#define EXP_HID 64

// d_out layout (float32, concatenated in return order):
//   disen_graph_emb (K*HID = 256) | Z (N*K*HID = 12,800,000) |
//   e_h_final (E = 800,000)       | e_h_all (K*E = 3,200,000)
#define OFF_DISEN 0
#define OFF_Z     (KF*HID)
#define OFF_EHF   (OFF_Z + N_NODES*KF*HID)
#define OFF_EHALL (OFF_EHF + E_EDGES)

#define NPB 8                    // nodes per block in z_kernel (50000 = 6250*8)
#define NROWS (N_NODES * KF)     // 200000 (n,k) rows
#define PQ_ELEMS ((size_t)NROWS * EXP_HID)        // 12.8M floats each
#define PQ_BYTES (2 * PQ_ELEMS * sizeof(float))   // 102.4 MB

// ---------------------------------------------------------------------------
// Kernel 1: Z[n,k,h] = relu(x[n,:] @ W_init[k,:,h] + b_init[k,h]), row-
// normalized over h. 4 waves/block (wave = k), 8 nodes/block; x staged in
// LDS read back as uniform-broadcast ds_read_b128 (4 i's per read).
// ---------------------------------------------------------------------------
__global__ __launch_bounds__(256) void z_kernel(
    const float* __restrict__ x, const float* __restrict__ W,
    const float* __restrict__ b, float* __restrict__ out) {
  __shared__ __align__(16) float xs[NPB * IN_DIM];
  const int tid = threadIdx.x;
  const int n0 = blockIdx.x * NPB;

  ((float4*)xs)[tid] = ((const float4*)(x + n0 * IN_DIM))[tid];
  __syncthreads();

  const int k = tid >> 6;
  const int h = tid & 63;

  const float bias = b[k * HID + h];
  float acc[NPB];
#pragma unroll
  for (int j = 0; j < NPB; ++j) acc[j] = bias;

  const float* wp = W + k * IN_DIM * HID + h;   // coalesced over h
#pragma unroll 4
  for (int i4 = 0; i4 < IN_DIM / 4; ++i4) {
    const float w0 = wp[(i4 * 4 + 0) * HID];
    const float w1 = wp[(i4 * 4 + 1) * HID];
    const float w2 = wp[(i4 * 4 + 2) * HID];
    const float w3 = wp[(i4 * 4 + 3) * HID];
#pragma unroll
    for (int j = 0; j < NPB; ++j) {
      const float4 xv = ((const float4*)(xs + j * IN_DIM))[i4];  // broadcast
      acc[j] = fmaf(xv.x, w0, acc[j]);
      acc[j] = fmaf(xv.y, w1, acc[j]);
      acc[j] = fmaf(xv.z, w2, acc[j]);
      acc[j] = fmaf(xv.w, w3, acc[j]);
    }
  }

  float* zout = out + OFF_Z + n0 * (KF * HID) + k * HID + h;
#pragma unroll
  for (int j = 0; j < NPB; ++j) {
    float z = fmaxf(acc[j], 0.f);
    float s = z * z;
#pragma unroll
    for (int d = 1; d < 64; d <<= 1) s += __shfl_xor(s, d, 64);
    zout[j * (KF * HID)] = z / fmaxf(sqrtf(s), 1e-12f);
  }
}

// ---------------------------------------------------------------------------
// Kernel 2a/2b: disen_graph_emb[k,h] = max_n Z[n,k,h]. Z >= 0 so uint-punned
// atomicMax is exact and order-independent.
// ---------------------------------------------------------------------------
__global__ void disen_init_kernel(float* __restrict__ disen) {
  disen[threadIdx.x] = 0.f;
}

__global__ __launch_bounds__(256) void disen_max_kernel(
    const float* __restrict__ Z, float* __restrict__ disen) {
  const int tid = threadIdx.x;
  const int chunk = (N_NODES + gridDim.x - 1) / gridDim.x;
  const int s = blockIdx.x * chunk;
  const int e = min(s + chunk, N_NODES);
  float m = 0.f;
#pragma unroll 4
  for (int n = s; n < e; ++n)
    m = fmaxf(m, Z[n * (KF * HID) + tid]);
  atomicMax((unsigned int*)(disen + tid), __float_as_uint(m));
}

// ---------------------------------------------------------------------------
// Kernel 3: P[n,k,o] = b1[o] + sum_h Z[n,k,h] W1s[h,o]
//           Q[n,k,o] =         sum_h Z[n,k,h] W1d[h,o]
// lane = o; W1 columns held in registers (128 VGPR), Z tiles staged in LDS
// and read as uniform broadcasts. 3125 blocks x 64 rows each.
// ---------------------------------------------------------------------------
__global__ __launch_bounds__(256) void pq_kernel(
    const float* __restrict__ Z, const float* __restrict__ W1,
    const float* __restrict__ b1, float* __restrict__ P,
    float* __restrict__ Q) {
  __shared__ __align__(16) float zt[16 * HID];   // 16-row tile
  const int tid = threadIdx.x;
  const int lane = tid & 63;
  const int w = tid >> 6;

  float ws[HID], wd[HID];
#pragma unroll
  for (int h = 0; h < HID; ++h) {
    ws[h] = W1[h * EXP_HID + lane];              // coalesced
    wd[h] = W1[(HID + h) * EXP_HID + lane];
  }
  const float bb = b1[lane];

  const int rpb = NROWS / gridDim.x;             // 64 rows per block
  const int base = blockIdx.x * rpb;
  for (int t = 0; t < rpb; t += 16) {
    __syncthreads();
    ((float4*)zt)[tid] = ((const float4*)(Z + (size_t)(base + t) * HID))[tid];
    __syncthreads();
#pragma unroll
    for (int r = 0; r < 4; ++r) {
      const int row = w * 4 + r;
      float accP = bb, accQ = 0.f;
      const float4* z4 = (const float4*)(zt + row * HID);
#pragma unroll
      for (int h4 = 0; h4 < 16; ++h4) {
        const float4 z = z4[h4];                 // uniform broadcast
        accP = fmaf(z.x, ws[h4 * 4 + 0], accP);
        accQ = fmaf(z.x, wd[h4 * 4 + 0], accQ);
        accP = fmaf(z.y, ws[h4 * 4 + 1], accP);
        accQ = fmaf(z.y, wd[h4 * 4 + 1], accQ);
        accP = fmaf(z.z, ws[h4 * 4 + 2], accP);
        accQ = fmaf(z.z, wd[h4 * 4 + 2], accQ);
        accP = fmaf(z.w, ws[h4 * 4 + 3], accP);
        accQ = fmaf(z.w, wd[h4 * 4 + 3], accQ);
      }
      const size_t orow = (size_t)(base + t + row) * EXP_HID + lane;
      P[orow] = accP;
      Q[orow] = accQ;
    }
  }
}

// ---------------------------------------------------------------------------
// Kernel 4: one thread per (edge,k): ek = W2 . relu(P[src,k,:]+Q[dst,k,:]) + b2
// 32 float4 gathers in flight per thread; quad shuffle-max for e_h_final.
// ---------------------------------------------------------------------------
__global__ __launch_bounds__(256) void edge_kernel2(
    const int* __restrict__ ei, const float* __restrict__ W2,
    const float* __restrict__ b2, const float* __restrict__ P,
    const float* __restrict__ Q, float* __restrict__ ehf,
    float* __restrict__ ehall) {
  __shared__ __align__(16) float w2s[EXP_HID];
  const int tid = threadIdx.x;
  if (tid < EXP_HID) w2s[tid] = W2[tid];
  __syncthreads();

  const int gid = blockIdx.x * 256 + tid;        // [0, E*K)
  const int e = gid >> 2;
  const int k = gid & 3;
  const int src = ei[e];
  const int dst = ei[E_EDGES + e];

  const float4* p4 = (const float4*)(P + ((size_t)src * KF + k) * EXP_HID);
  const float4* q4 = (const float4*)(Q + ((size_t)dst * KF + k) * EXP_HID);

  float4 pv[16], qv[16];
#pragma unroll
  for (int i = 0; i < 16; ++i) pv[i] = p4[i];
#pragma unroll
  for (int i = 0; i < 16; ++i) qv[i] = q4[i];

  float e0 = b2[0], e1 = 0.f, e2 = 0.f, e3 = 0.f;
#pragma unroll
  for (int i = 0; i < 16; ++i) {
    const float4 w = ((const float4*)w2s)[i];    // uniform broadcast
    e0 = fmaf(fmaxf(pv[i].x + qv[i].x, 0.f), w.x, e0);
    e1 = fmaf(fmaxf(pv[i].y + qv[i].y, 0.f), w.y, e1);
    e2 = fmaf(fmaxf(pv[i].z + qv[i].z, 0.f), w.z, e2);
    e3 = fmaf(fmaxf(pv[i].w + qv[i].w, 0.f), w.w, e3);
  }
  const float ek = (e0 + e1) + (e2 + e3);

  ehall[(size_t)k * E_EDGES + e] = ek;

  float m = fmaxf(ek, __shfl_xor(ek, 1, 64));
  m = fmaxf(m, __shfl_xor(m, 2, 64));
  if (k == 0) ehf[e] = m;
}

// ---------------------------------------------------------------------------
// Fallback edge kernel (round-1 version) if d_ws is too small for P/Q.
// ---------------------------------------------------------------------------
__global__ __launch_bounds__(256) void edge_kernel_fb(
    const int* __restrict__ ei, const float* __restrict__ W1,
    const float* __restrict__ b1, const float* __restrict__ W2,
    const float* __restrict__ b2, const float* __restrict__ Z,
    float* __restrict__ ehf, float* __restrict__ ehall) {
  __shared__ __align__(16) float w1s[HID * EXP_HID];
  __shared__ __align__(16) float w1d[HID * EXP_HID];
  __shared__ __align__(16) float w2s[EXP_HID];
  __shared__ __align__(16) float b1s[EXP_HID];

  const int tid = threadIdx.x;
#pragma unroll
  for (int r = 0; r < 4; ++r)
    ((float4*)w1s)[r * 256 + tid] = ((const float4*)W1)[r * 256 + tid];
#pragma unroll
  for (int r = 0; r < 4; ++r)
    ((float4*)w1d)[r * 256 + tid] =
        ((const float4*)(W1 + HID * EXP_HID))[r * 256 + tid];
  if (tid < EXP_HID) { w2s[tid] = W2[tid]; b1s[tid] = b1[tid]; }
  __syncthreads();

  const float bias2 = b2[0];
  const int e = blockIdx.x * 256 + tid;
  const int src = ei[e];
  const int dst = ei[E_EDGES + e];
  const float* zs_base = Z + src * (KF * HID);
  const float* zd_base = Z + dst * (KF * HID);

  float m = -INFINITY;
#pragma unroll 1
  for (int k = 0; k < KF; ++k) {
    const float4* zs4 = (const float4*)(zs_base + k * HID);
    const float4* zd4 = (const float4*)(zd_base + k * HID);
    float acc[EXP_HID];
#pragma unroll
    for (int o4 = 0; o4 < 16; ++o4) {
      const float4 bb = ((const float4*)b1s)[o4];
      acc[o4 * 4 + 0] = bb.x; acc[o4 * 4 + 1] = bb.y;
      acc[o4 * 4 + 2] = bb.z; acc[o4 * 4 + 3] = bb.w;
    }
#pragma unroll 1
    for (int h4 = 0; h4 < 16; ++h4) {
      const float4 a = zs4[h4];
      const float4 c = zd4[h4];
#pragma unroll
      for (int j = 0; j < 4; ++j) {
        const int h = h4 * 4 + j;
        const float as = (&a.x)[j];
        const float ad = (&c.x)[j];
        const float4* wsp = (const float4*)(w1s + h * EXP_HID);
        const float4* wdp = (const float4*)(w1d + h * EXP_HID);
#pragma unroll
        for (int o4 = 0; o4 < 16; ++o4) {
          const float4 w = wsp[o4];
          acc[o4 * 4 + 0] = fmaf(as, w.x, acc[o4 * 4 + 0]);
          acc[o4 * 4 + 1] = fmaf(as, w.y, acc[o4 * 4 + 1]);
          acc[o4 * 4 + 2] = fmaf(as, w.z, acc[o4 * 4 + 2]);
          acc[o4 * 4 + 3] = fmaf(as, w.w, acc[o4 * 4 + 3]);
          const float4 v = wdp[o4];
          acc[o4 * 4 + 0] = fmaf(ad, v.x, acc[o4 * 4 + 0]);
          acc[o4 * 4 + 1] = fmaf(ad, v.y, acc[o4 * 4 + 1]);
          acc[o4 * 4 + 2] = fmaf(ad, v.z, acc[o4 * 4 + 2]);
          acc[o4 * 4 + 3] = fmaf(ad, v.w, acc[o4 * 4 + 3]);
        }
      }
    }
    float ek = bias2;
#pragma unroll
    for (int o = 0; o < EXP_HID; ++o)
      ek = fmaf(fmaxf(acc[o], 0.f), w2s[o], ek);
    ehall[k * E_EDGES + e] = ek;
    m = fmaxf(m, ek);
  }
  ehf[e] = m;
}

// ---------------------------------------------------------------------------
extern "C" void kernel_launch(void* const* d_in, const int* in_sizes, int n_in,
                              void* d_out, int out_size, void* d_ws,
                              size_t ws_size, hipStream_t stream) {
  const float* x      = (const float*)d_in[0];
  const int*   ei     = (const int*)  d_in[1];
  const float* W_init = (const float*)d_in[2];
  const float* b_init = (const float*)d_in[3];
  const float* W1     = (const float*)d_in[4];
  const float* b1     = (const float*)d_in[5];
  const float* W2     = (const float*)d_in[6];
  const float* b2     = (const float*)d_in[7];
  float* out = (float*)d_out;

  z_kernel<<<N_NODES / NPB, 256, 0, stream>>>(x, W_init, b_init, out);
  disen_init_kernel<<<1, KF * HID, 0, stream>>>(out + OFF_DISEN);
  disen_max_kernel<<<256, 256, 0, stream>>>(out + OFF_Z, out + OFF_DISEN);

  if (ws_size >= PQ_BYTES) {
    float* P = (float*)d_ws;
    float* Q = P + PQ_ELEMS;
    pq_kernel<<<3125, 256, 0, stream>>>(out + OFF_Z, W1, b1, P, Q);
    edge_kernel2<<<(E_EDGES * KF) / 256, 256, 0, stream>>>(
        ei, W2, b2, P, Q, out + OFF_EHF, out + OFF_EHALL);
  } else {
    edge_kernel_fb<<<E_EDGES / 256, 256, 0, stream>>>(
        ei, W1, b1, W2, b2, out + OFF_Z, out + OFF_EHF, out + OFF_EHALL);
  }
}

// Round 3
// 349.992 us; speedup vs baseline: 5.0462x; 1.8153x over previous
//
#include <hip/hip_runtime.h>
#include <hip/hip_bf16.h>
#include <math.h>

#define N_NODES 50000
#define E_EDGES 800000
#define IN_DIM  128
#define HID     64
#define KF      4
#define EXP_HID 64

// d_out layout (float32, concatenated in return order):
//   disen_graph_emb (K*HID = 256) | Z (N*K*HID = 12,800,000) |
//   e_h_final (E = 800,000)       | e_h_all (K*E = 3,200,000)
#define OFF_DISEN 0
#define OFF_Z     (KF*HID)
#define OFF_EHF   (OFF_Z + N_NODES*KF*HID)
#define OFF_EHALL (OFF_EHF + E_EDGES)

#define NPB 8                    // nodes per block in z_kernel (50000 = 6250*8)
#define NROWS (N_NODES * KF)     // 200000 (n,k) rows
#define PQ_ELEMS ((size_t)NROWS * EXP_HID)          // 12.8M elems each
#define PQ_BYTES_BF16 (2 * PQ_ELEMS * sizeof(unsigned short))  // 51.2 MB

// ---------------------------------------------------------------------------
// Kernel 1: Z[n,k,h] = relu(x[n,:] @ W_init[k,:,h] + b_init[k,h]), row-
// normalized over h. 4 waves/block (wave = k), 8 nodes/block; x staged in
// LDS, read back as uniform-broadcast ds_read_b128.
// ---------------------------------------------------------------------------
__global__ __launch_bounds__(256) void z_kernel(
    const float* __restrict__ x, const float* __restrict__ W,
    const float* __restrict__ b, float* __restrict__ out) {
  __shared__ __align__(16) float xs[NPB * IN_DIM];
  const int tid = threadIdx.x;
  const int n0 = blockIdx.x * NPB;

  ((float4*)xs)[tid] = ((const float4*)(x + n0 * IN_DIM))[tid];
  __syncthreads();

  const int k = tid >> 6;
  const int h = tid & 63;

  const float bias = b[k * HID + h];
  float acc[NPB];
#pragma unroll
  for (int j = 0; j < NPB; ++j) acc[j] = bias;

  const float* wp = W + k * IN_DIM * HID + h;   // coalesced over h
#pragma unroll 4
  for (int i4 = 0; i4 < IN_DIM / 4; ++i4) {
    const float w0 = wp[(i4 * 4 + 0) * HID];
    const float w1 = wp[(i4 * 4 + 1) * HID];
    const float w2 = wp[(i4 * 4 + 2) * HID];
    const float w3 = wp[(i4 * 4 + 3) * HID];
#pragma unroll
    for (int j = 0; j < NPB; ++j) {
      const float4 xv = ((const float4*)(xs + j * IN_DIM))[i4];  // broadcast
      acc[j] = fmaf(xv.x, w0, acc[j]);
      acc[j] = fmaf(xv.y, w1, acc[j]);
      acc[j] = fmaf(xv.z, w2, acc[j]);
      acc[j] = fmaf(xv.w, w3, acc[j]);
    }
  }

  float* zout = out + OFF_Z + n0 * (KF * HID) + k * HID + h;
#pragma unroll
  for (int j = 0; j < NPB; ++j) {
    float z = fmaxf(acc[j], 0.f);
    float s = z * z;
#pragma unroll
    for (int d = 1; d < 64; d <<= 1) s += __shfl_xor(s, d, 64);
    zout[j * (KF * HID)] = z / fmaxf(sqrtf(s), 1e-12f);
  }
}

// ---------------------------------------------------------------------------
// Kernel 2a/2b: disen_graph_emb[k,h] = max_n Z[n,k,h]. Z >= 0 so uint-punned
// atomicMax is exact and order-independent.
// ---------------------------------------------------------------------------
__global__ void disen_init_kernel(float* __restrict__ disen) {
  disen[threadIdx.x] = 0.f;
}

__global__ __launch_bounds__(256) void disen_max_kernel(
    const float* __restrict__ Z, float* __restrict__ disen) {
  const int tid = threadIdx.x;
  const int chunk = (N_NODES + gridDim.x - 1) / gridDim.x;
  const int s = blockIdx.x * chunk;
  const int e = min(s + chunk, N_NODES);
  float m = 0.f;
#pragma unroll 4
  for (int n = s; n < e; ++n)
    m = fmaxf(m, Z[n * (KF * HID) + tid]);
  atomicMax((unsigned int*)(disen + tid), __float_as_uint(m));
}

// ---------------------------------------------------------------------------
// Kernel 3: P[n,k,o] = b1[o] + sum_h Z[n,k,h] W1s[h,o]   (stored bf16)
//           Q[n,k,o] =         sum_h Z[n,k,h] W1d[h,o]   (stored bf16)
// lane = o; W1 columns in registers, Z tiles staged in LDS (broadcast reads).
// ---------------------------------------------------------------------------
__global__ __launch_bounds__(256) void pq_kernel(
    const float* __restrict__ Z, const float* __restrict__ W1,
    const float* __restrict__ b1, unsigned short* __restrict__ P,
    unsigned short* __restrict__ Q) {
  __shared__ __align__(16) float zt[16 * HID];   // 16-row tile
  const int tid = threadIdx.x;
  const int lane = tid & 63;
  const int w = tid >> 6;

  float ws[HID], wd[HID];
#pragma unroll
  for (int h = 0; h < HID; ++h) {
    ws[h] = W1[h * EXP_HID + lane];              // coalesced
    wd[h] = W1[(HID + h) * EXP_HID + lane];
  }
  const float bb = b1[lane];

  const int rpb = NROWS / gridDim.x;             // 64 rows per block
  const int base = blockIdx.x * rpb;
  for (int t = 0; t < rpb; t += 16) {
    __syncthreads();
    ((float4*)zt)[tid] = ((const float4*)(Z + (size_t)(base + t) * HID))[tid];
    __syncthreads();
#pragma unroll
    for (int r = 0; r < 4; ++r) {
      const int row = w * 4 + r;
      float accP = bb, accQ = 0.f;
      const float4* z4 = (const float4*)(zt + row * HID);
#pragma unroll
      for (int h4 = 0; h4 < 16; ++h4) {
        const float4 z = z4[h4];                 // uniform broadcast
        accP = fmaf(z.x, ws[h4 * 4 + 0], accP);
        accQ = fmaf(z.x, wd[h4 * 4 + 0], accQ);
        accP = fmaf(z.y, ws[h4 * 4 + 1], accP);
        accQ = fmaf(z.y, wd[h4 * 4 + 1], accQ);
        accP = fmaf(z.z, ws[h4 * 4 + 2], accP);
        accQ = fmaf(z.z, wd[h4 * 4 + 2], accQ);
        accP = fmaf(z.w, ws[h4 * 4 + 3], accP);
        accQ = fmaf(z.w, wd[h4 * 4 + 3], accQ);
      }
      const size_t orow = (size_t)(base + t + row) * EXP_HID + lane;
      __hip_bfloat16 hp = __float2bfloat16(accP);   // RNE
      __hip_bfloat16 hq = __float2bfloat16(accQ);
      P[orow] = *(unsigned short*)&hp;
      Q[orow] = *(unsigned short*)&hq;
    }
  }
}

// ---------------------------------------------------------------------------
// Kernel 4: one thread per (edge,k):
//   ek = W2 . relu(bf16(P[src,k,:]) + bf16(Q[dst,k,:])) + b2
// 8+8 uint4 (16B) gathers per thread; bf16 unpack is 2 bit-ops per pair
// (exact). Quad shuffle-max for e_h_final.
// ---------------------------------------------------------------------------
__global__ __launch_bounds__(256) void edge_kernel3(
    const int* __restrict__ ei, const float* __restrict__ W2,
    const float* __restrict__ b2, const unsigned short* __restrict__ P,
    const unsigned short* __restrict__ Q, float* __restrict__ ehf,
    float* __restrict__ ehall) {
  __shared__ __align__(16) float w2s[EXP_HID];
  const int tid = threadIdx.x;
  if (tid < EXP_HID) w2s[tid] = W2[tid];
  __syncthreads();

  const int gid = blockIdx.x * 256 + tid;        // [0, E*K)
  const int e = gid >> 2;
  const int k = gid & 3;
  const int src = ei[e];
  const int dst = ei[E_EDGES + e];

  const uint4* p4 = (const uint4*)(P + ((size_t)src * KF + k) * EXP_HID);
  const uint4* q4 = (const uint4*)(Q + ((size_t)dst * KF + k) * EXP_HID);

  uint4 pv[8], qv[8];
#pragma unroll
  for (int i = 0; i < 8; ++i) pv[i] = p4[i];     // 128B contiguous per row
#pragma unroll
  for (int i = 0; i < 8; ++i) qv[i] = q4[i];

  float acc = b2[0];
#pragma unroll
  for (int i = 0; i < 8; ++i) {
    const unsigned int* pu = (const unsigned int*)&pv[i];
    const unsigned int* qu = (const unsigned int*)&qv[i];
#pragma unroll
    for (int j = 0; j < 4; ++j) {
      const unsigned int up = pu[j], uq = qu[j];
      const float p0 = __uint_as_float(up << 16);           // exact
      const float p1 = __uint_as_float(up & 0xffff0000u);   // exact
      const float q0 = __uint_as_float(uq << 16);
      const float q1 = __uint_as_float(uq & 0xffff0000u);
      const int o = i * 8 + j * 2;
      acc = fmaf(fmaxf(p0 + q0, 0.f), w2s[o], acc);     // broadcast LDS
      acc = fmaf(fmaxf(p1 + q1, 0.f), w2s[o + 1], acc);
    }
  }

  ehall[(size_t)k * E_EDGES + e] = acc;

  float m = fmaxf(acc, __shfl_xor(acc, 1, 64));
  m = fmaxf(m, __shfl_xor(m, 2, 64));
  if (k == 0) ehf[e] = m;
}

// ---------------------------------------------------------------------------
extern "C" void kernel_launch(void* const* d_in, const int* in_sizes, int n_in,
                              void* d_out, int out_size, void* d_ws,
                              size_t ws_size, hipStream_t stream) {
  const float* x      = (const float*)d_in[0];
  const int*   ei     = (const int*)  d_in[1];
  const float* W_init = (const float*)d_in[2];
  const float* b_init = (const float*)d_in[3];
  const float* W1     = (const float*)d_in[4];
  const float* b1     = (const float*)d_in[5];
  const float* W2     = (const float*)d_in[6];
  const float* b2     = (const float*)d_in[7];
  float* out = (float*)d_out;

  unsigned short* P = (unsigned short*)d_ws;     // ws >= 102.4MB (verified r2)
  unsigned short* Q = P + PQ_ELEMS;

  z_kernel<<<N_NODES / NPB, 256, 0, stream>>>(x, W_init, b_init, out);
  disen_init_kernel<<<1, KF * HID, 0, stream>>>(out + OFF_DISEN);
  disen_max_kernel<<<256, 256, 0, stream>>>(out + OFF_Z, out + OFF_DISEN);
  pq_kernel<<<3125, 256, 0, stream>>>(out + OFF_Z, W1, b1, P, Q);
  edge_kernel3<<<(E_EDGES * KF) / 256, 256, 0, stream>>>(
      ei, W2, b2, P, Q, out + OFF_EHF, out + OFF_EHALL);
}